// Round 3
// baseline (4772.311 us; speedup 1.0000x reference)
//
#include <hip/hip_runtime.h>
#include <hip/hip_bf16.h>

#define BB   1024
#define TT   64
#define IND  64
#define HH   512
#define G4   2048   // 4*H
#define NLAYER 8
#define NCLS 128
#define KP   1024   // packed W k-stride: k<512 = W_hh, k>=512 = W_ih (layer0 64 + pad)
#define RS   8      // ring slots per layer (reuse distance 8 = fence period)
#define SLOT (32 * 1024 * 16)  // elements per h slot: [by=32][b=1024][jj=16]

typedef __bf16 bf16x8 __attribute__((ext_vector_type(8)));
typedef float  f32x4  __attribute__((ext_vector_type(4)));

typedef const __attribute__((address_space(1))) void* as1cvp;
typedef __attribute__((address_space(3))) void* as3vp;

__device__ __forceinline__ void gload16(void* lds, const void* g) {
  __builtin_amdgcn_global_load_lds((as1cvp)g, (as3vp)lds, 16, 0, 0);
}

__device__ __forceinline__ float sigmf(float x) { return 1.f / (1.f + __expf(-x)); }
__device__ __forceinline__ float tanhfast(float x) { return 2.f / (1.f + __expf(-2.f * x)) - 1.f; }

// ---------------- prep kernels ----------------
__global__ void cvt_kernel(const float* __restrict__ s, __bf16* __restrict__ d, int n) {
  int i = blockIdx.x * 256 + threadIdx.x;
  if (i < n) d[i] = (__bf16)s[i];
}

__global__ void pack_w(const float* __restrict__ whh0, const float* __restrict__ wih0,
                       const float* __restrict__ whh, const float* __restrict__ wih,
                       __bf16* __restrict__ Wp) {
  int i = blockIdx.x * 256 + threadIdx.x;  // 8*2048*1024
  int k = i & (KP - 1), n = (i >> 10) & 2047, l = i >> 21;
  float v;
  if (k < 512) v = (l == 0) ? whh0[n * 512 + k] : whh[((size_t)(l - 1) * G4 + n) * 512 + k];
  else if (l == 0) v = (k < 512 + IND) ? wih0[n * IND + (k - 512)] : 0.f;
  else v = wih[((size_t)(l - 1) * G4 + n) * 512 + (k - 512)];
  Wp[i] = (__bf16)v;
}

__global__ void bias_prep(const float* __restrict__ bi0, const float* __restrict__ bh0,
                          const float* __restrict__ bi, const float* __restrict__ bh,
                          float* __restrict__ biasb) {
  int i = blockIdx.x * 256 + threadIdx.x;  // 8*2048
  int l = i >> 11, k = i & 2047;
  float v = (l == 0) ? (bi0[k] + bh0[k]) : (bi[(l - 1) * G4 + k] + bh[(l - 1) * G4 + k]);
  biasb[i] = v;
}

__global__ void zero_u32(unsigned* __restrict__ p, int n) {
  int i = blockIdx.x * 256 + threadIdx.x;
  if (i < n) p[i] = 0u;
}

// ---------------- all-layers pipelined LSTM ----------------
// R13 = R12 structure with: 512-thread blocks (1/CU, 32/XCD), the FULL packed W
// row-panel (64 n-rows x 1024 k = 128KB) resident in LDS (32 XOR-swizzled
// k-slices), and a full-kt depth-2 A pipeline (A0[8]/A1[8], prefetch kt+2).
// Rationale: R12's half-kt rotation covers ~600cy (L2) but not cross-XCD IF$
// (~900cy); W-in-LDS frees the 32 W-rotation VGPRs to fund depth-2 (cover
// ~1240cy wall > HBM-miss). W global traffic in the K-loop drops to zero.
// Wave tile (128b x 64n), acc=128 AGPR, MFMA order per accumulator, sync scheme
// (flags / RS=8 ring / acquire fence per period / B2 back-pressure / B3 drain)
// all unchanged from proven R10/R12 -> bit-identical numerics.
__global__ __launch_bounds__(512, 2) void lstm_all(
    const float* __restrict__ xf,      // [B][T][64] fp32
    const __bf16* __restrict__ Wp,     // [8][2048][KP]
    const float* __restrict__ biasb,   // [8][2048]
    __bf16* __restrict__ hring,        // [7][RS][SLOT]
    __bf16* __restrict__ h7,           // [64][SLOT]
    unsigned* __restrict__ flags,      // [8][64] (32 used per layer)
    unsigned* __restrict__ xslot) {    // [8]
  extern __shared__ __bf16 Wlds[];     // 128KB: 32 k-slices x (64 rows x 32 k)
  __shared__ int sbs;
  const int tid = threadIdx.x;

  if (tid == 0) {
    unsigned xcc;
    asm volatile("s_getreg_b32 %0, hwreg(HW_REG_XCC_ID)" : "=s"(xcc));
    xcc &= 7u;
    unsigned slot = __hip_atomic_fetch_add(xslot + xcc, 1u, __ATOMIC_RELAXED,
                                           __HIP_MEMORY_SCOPE_AGENT) & 31u;
    sbs = (int)((xcc << 5) | slot);
  }
  __syncthreads();
  const int l  = sbs >> 5;         // layer = XCD
  const int by = sbs & 31;         // j-tile (16 j x 4 gates)
  const int j0 = by << 4;
  const __bf16* Wl = Wp + (size_t)l * G4 * KP;

  // ---- stage full W panel (64 n-rows x 1024 k) into LDS, XOR-swizzled.
  // slice kt<16 = W_hh (k<512); kt>=16 = W_ih (k>=512).
  for (int it = 0; it < 16; ++it) {
    const int p = it * 512 + tid;           // granule 0..8191
    const int kt = p >> 8;                  // k-slice 0..31
    const int q = p & 255;
    const int u = q >> 2;                   // row 0..63 (gate*16+jj)
    const int g = (q & 3) ^ ((u >> 1) & 3);
    const int n = ((u >> 4) << 9) + j0 + (u & 15);
    gload16(&Wlds[p * 8], Wl + (size_t)n * KP + kt * 32 + g * 8);
  }

  const int lane = tid & 63, wv = tid >> 6;
  const int qr = lane >> 4, ml = lane & 15;
  float bv[4];
  int wsw[4];
#pragma unroll
  for (int g = 0; g < 4; ++g) {
    const int n = g * 512 + j0 + ml;
    bv[g] = biasb[l * G4 + n];
    const int u = g * 16 + ml;
    wsw[g] = u * 32 + ((qr ^ ((u >> 1) & 3)) << 3);
  }
  const int r0 = wv << 7;                 // wave's 128 rows (8 m-tiles of 16)
  const int rowA = r0 + ml;
  // A-frag base offset into a slot: (kt*2 + (qr>>1))*16384 + row*16 + (qr&1)*8
  const int abase = ((qr >> 1) << 14) + rowA * 16 + ((qr & 1) << 3);
  __bf16* ringL = hring + (size_t)l * RS * SLOT;                       // l<7
  const __bf16* ringU = hring + (size_t)((l > 0 ? l : 1) - 1) * RS * SLOT;
  unsigned* ownf = flags + l * 64;
  unsigned* upf  = flags + (l > 0 ? l - 1 : 0) * 64;
  unsigned* dnf  = flags + (l < 7 ? l + 1 : 7) * 64;
  float c8[8][4] = {};
  __syncthreads();  // W staged

  for (int t = 0; t < TT; ++t) {
    // ---- B1: combined wait (own >= t, upstream >= t+1), wave 0 only
    if (wv == 0) {
      const bool isown = (lane < 32);
      const unsigned* fp = isown ? (ownf + lane) : (upf + (lane - 32));
      const unsigned need = isown ? (unsigned)t : (unsigned)(t + 1);
      const bool act = isown ? (t > 0) : (l > 0);
      for (;;) {
        unsigned v = act ? __hip_atomic_load(fp, __ATOMIC_RELAXED,
                                             __HIP_MEMORY_SCOPE_AGENT)
                         : need;
        if (__all((int)(v >= need))) break;
        __builtin_amdgcn_s_sleep(1);
      }
    }
    __syncthreads();
    if (t > 0 && (t & (RS - 1)) == 0)
      __builtin_amdgcn_fence(__ATOMIC_ACQUIRE, "agent");  // once per ring period

    // ---- acc init (bias)
    f32x4 acc[8][4];
#pragma unroll
    for (int m = 0; m < 8; ++m)
#pragma unroll
      for (int g = 0; g < 4; ++g)
#pragma unroll
        for (int r = 0; r < 4; ++r) acc[m][g][r] = bv[g];

    const __bf16* srcX = ringU + (size_t)(t & (RS - 1)) * SLOT + abase;
    const __bf16* srcH = ((l < 7)
        ? ringL + (size_t)((t > 0 ? t - 1 : 0) & (RS - 1)) * SLOT
        : h7 + (size_t)(t > 0 ? t - 1 : 0) * SLOT) + abase;

    bf16x8 A0[8], A1[8];
    auto loadA = [&](bf16x8 (&A)[8], const __bf16* s) {
#pragma unroll
      for (int m = 0; m < 8; ++m) A[m] = *(const bf16x8*)(s + m * 256);
    };
    auto cluster = [&](const bf16x8 (&A)[8], const int slice) {
#pragma unroll
      for (int g = 0; g < 4; ++g) {
        const bf16x8 wf = *(const bf16x8*)&Wlds[slice * 2048 + wsw[g]];
#pragma unroll
        for (int m = 0; m < 8; ++m)
          acc[m][g] = __builtin_amdgcn_mfma_f32_16x16x32_bf16(A[m], wf, acc[m][g], 0, 0, 0);
      }
    };

    if (l == 0) {
      // ---- layer-0 x-part: direct fp32->bf16, K=64; W_ih from LDS slices 16,17
      bf16x8 w16[4], w17[4];
#pragma unroll
      for (int g = 0; g < 4; ++g) {
        w16[g] = *(const bf16x8*)&Wlds[16 * 2048 + wsw[g]];
        w17[g] = *(const bf16x8*)&Wlds[17 * 2048 + wsw[g]];
      }
#pragma unroll
      for (int m = 0; m < 8; ++m) {
        const float* xr = xf + ((size_t)(rowA + m * 16) * TT + t) * IND + qr * 8;
        const f32x4 f0 = *(const f32x4*)xr;
        const f32x4 f1 = *(const f32x4*)(xr + 4);
        const f32x4 f2 = *(const f32x4*)(xr + 32);
        const f32x4 f3 = *(const f32x4*)(xr + 36);
        bf16x8 a0, a1;
#pragma unroll
        for (int r = 0; r < 4; ++r) {
          a0[r] = (__bf16)f0[r]; a0[4 + r] = (__bf16)f1[r];
          a1[r] = (__bf16)f2[r]; a1[4 + r] = (__bf16)f3[r];
        }
#pragma unroll
        for (int g = 0; g < 4; ++g) {
          acc[m][g] = __builtin_amdgcn_mfma_f32_16x16x32_bf16(a0, w16[g], acc[m][g], 0, 0, 0);
          acc[m][g] = __builtin_amdgcn_mfma_f32_16x16x32_bf16(a1, w17[g], acc[m][g], 0, 0, 0);
        }
      }
      if (t > 0) { loadA(A0, srcH); loadA(A1, srcH + 32768); }
    } else {
      // ---- x-part (upstream h[t], W slices 16..31), depth-2 full-kt pipeline
      loadA(A0, srcX);
      loadA(A1, srcX + 32768);
#pragma unroll
      for (int k2 = 0; k2 < 8; ++k2) {
        cluster(A0, 16 + 2 * k2);
        { const int nk = 2 * k2 + 2;
          loadA(A0, (nk < 16) ? srcX + nk * 32768 : srcH + (nk - 16) * 32768); }
        __builtin_amdgcn_sched_barrier(0);
        cluster(A1, 16 + 2 * k2 + 1);
        { const int nk = 2 * k2 + 3;
          loadA(A1, (nk < 16) ? srcX + nk * 32768 : srcH + (nk - 16) * 32768); }
        __builtin_amdgcn_sched_barrier(0);
      }
    }

    // ---- h-part (t>0): A = own h[t-1], W slices 0..15
    if (t > 0) {
#pragma unroll
      for (int k2 = 0; k2 < 8; ++k2) {
        cluster(A0, 2 * k2);
        if (2 * k2 + 2 < 16) loadA(A0, srcH + (2 * k2 + 2) * 32768);
        __builtin_amdgcn_sched_barrier(0);
        cluster(A1, 2 * k2 + 1);
        if (2 * k2 + 3 < 16) loadA(A1, srcH + (2 * k2 + 3) * 32768);
        __builtin_amdgcn_sched_barrier(0);
      }
    }

    // ---- ring back-pressure (overwrite slot t&7 only after downstream read gen t-8)
    if (wv == 0 && l < 7 && t >= RS) {
      const unsigned need = (unsigned)(t - (RS - 1));
      for (;;) {
        unsigned v = (lane < 32) ? __hip_atomic_load(dnf + lane, __ATOMIC_RELAXED,
                                                     __HIP_MEMORY_SCOPE_AGENT)
                                 : need;
        if (__all((int)(v >= need))) break;
        __builtin_amdgcn_s_sleep(1);
      }
    }
    __syncthreads();  // B2

    // ---- activations + h store: [by][b][16] panel -> contiguous 32B granules
    unsigned short* dst = (unsigned short*)(((l < 7)
        ? ringL + (size_t)(t & (RS - 1)) * SLOT
        : h7 + (size_t)t * SLOT) + ((size_t)by << 14)) + ml;
#pragma unroll
    for (int m = 0; m < 8; ++m) {
      const int rbm = r0 + m * 16 + (qr << 2);
#pragma unroll
      for (int r = 0; r < 4; ++r) {
        const float gi = sigmf(acc[m][0][r]);
        const float gf = sigmf(acc[m][1][r]);
        const float gg = tanhfast(acc[m][2][r]);
        const float go = sigmf(acc[m][3][r]);
        const float cv = gf * c8[m][r] + gi * gg;
        c8[m][r] = cv;
        const __bf16 hv = (__bf16)(go * tanhfast(cv));
        __hip_atomic_store(dst + (size_t)(rbm + r) * 16,
                           __builtin_bit_cast(unsigned short, hv),
                           __ATOMIC_RELAXED, __HIP_MEMORY_SCOPE_AGENT);
      }
    }
    __syncthreads();  // B3: drains vmcnt -> stores at coherence point
    if (tid == 0)
      __hip_atomic_store(ownf + by, (unsigned)(t + 1), __ATOMIC_RELAXED,
                         __HIP_MEMORY_SCOPE_AGENT);
  }
}

// ---------------- FC (bf16 MFMA, K-split; h7 in [t][by][b][16] layout) ----------------
__global__ __launch_bounds__(256, 2) void fc_kernel(
    const __bf16* __restrict__ hseq, const __bf16* __restrict__ fcw,
    float* __restrict__ partial) {
  __shared__ __bf16 At[64 * 32];
  __shared__ __bf16 Wt[128 * 32];
  const int tid = threadIdx.x;
  const int b0 = blockIdx.x * 64;
  const int kbase = blockIdx.y * 2048;
  const int lane = tid & 63, wv = tid >> 6;
  const int qr = lane >> 4, ml = lane & 15;
  const int wr = (wv >> 1) * 32, wc = (wv & 1) * 64;
  const int sr = tid >> 2, sk = (tid & 3) * 8;

  f32x4 acc[2][4];
  for (int i = 0; i < 2; i++)
    for (int j = 0; j < 4; j++)
      for (int r = 0; r < 4; r++) acc[i][j][r] = 0.f;

  for (int kt = 0; kt < 64; ++kt) {
    const int k = kbase + kt * 32;
    const int t = k >> 9;
    const int kk = (k & 511) + sk;      // global j index of this 8-elem chunk
    gload16(&At[tid * 8],
            hseq + (size_t)t * SLOT + ((size_t)(kk >> 4) * 1024 + b0 + sr) * 16 + (kk & 15));
    gload16(&Wt[tid * 8],        fcw + (size_t)sr * (TT * HH) + k + sk);
    gload16(&Wt[2048 + tid * 8], fcw + (size_t)(sr + 64) * (TT * HH) + k + sk);
    __syncthreads();
    bf16x8 af[2], bfr[4];
    for (int i = 0; i < 2; i++) af[i]  = *(const bf16x8*)&At[(wr + i * 16 + ml) * 32 + qr * 8];
    for (int j = 0; j < 4; j++) bfr[j] = *(const bf16x8*)&Wt[(wc + j * 16 + ml) * 32 + qr * 8];
    for (int i = 0; i < 2; i++)
      for (int j = 0; j < 4; j++)
        acc[i][j] = __builtin_amdgcn_mfma_f32_16x16x32_bf16(af[i], bfr[j], acc[i][j], 0, 0, 0);
    __syncthreads();
  }
  for (int i = 0; i < 2; i++)
    for (int j = 0; j < 4; j++)
      for (int r = 0; r < 4; r++)
        partial[((size_t)blockIdx.y * BB + b0 + wr + i * 16 + qr * 4 + r) * NCLS + wc + j * 16 + ml] =
            acc[i][j][r];
}

__global__ void fc_reduce(const float* __restrict__ partial, const float* __restrict__ fcb,
                          float* __restrict__ out) {
  int i = blockIdx.x * 256 + threadIdx.x;  // B*128
  float s = fcb[i & 127];
  for (int p = 0; p < 16; p++) s += partial[(size_t)p * (BB * NCLS) + i];
  out[i] = s;
}

// ---------------- host ----------------
extern "C" void kernel_launch(void* const* d_in, const int* in_sizes, int n_in,
                              void* d_out, int out_size, void* d_ws, size_t ws_size,
                              hipStream_t stream) {
  const float* x    = (const float*)d_in[0];
  const float* wih0 = (const float*)d_in[1];
  const float* whh0 = (const float*)d_in[2];
  const float* bih0 = (const float*)d_in[3];
  const float* bhh0 = (const float*)d_in[4];
  const float* wih  = (const float*)d_in[5];
  const float* whh  = (const float*)d_in[6];
  const float* bih  = (const float*)d_in[7];
  const float* bhh  = (const float*)d_in[8];
  const float* fcw  = (const float*)d_in[9];
  const float* fcb  = (const float*)d_in[10];
  float* out = (float*)d_out;

  hipFuncSetAttribute((const void*)lstm_all,
                      hipFuncAttributeMaxDynamicSharedMemorySize, 131072);

  size_t off = 0;
  char* base = (char*)d_ws;
  auto carve = [&](size_t bytes) -> char* {
    char* p = base + off;
    off += (bytes + 255) & ~(size_t)255;
    return p;
  };
  // total ~176 MB (< proven 193 MB budget)
  __bf16*   Wp    = (__bf16*)carve((size_t)NLAYER * G4 * KP * 2);      // 33.6 MB
  __bf16*   fcwb  = (__bf16*)carve((size_t)NCLS * TT * HH * 2);        //  8.4 MB
  float*    biasb = (float*)carve((size_t)NLAYER * G4 * 4);
  __bf16*   hring = (__bf16*)carve((size_t)7 * RS * SLOT * 2);         // 58.7 MB
  __bf16*   h7    = (__bf16*)carve((size_t)TT * SLOT * 2);             // 67.1 MB
  float*    part  = (float*)carve((size_t)16 * BB * NCLS * 4);         //  8.4 MB
  unsigned* flags = (unsigned*)carve((size_t)(NLAYER * 64 + 64) * 4);
  unsigned* xslot = flags + NLAYER * 64;

  // prep
  pack_w<<<(NLAYER * G4 * KP) / 256, 256, 0, stream>>>(whh0, wih0, whh, wih, Wp);
  cvt_kernel<<<(NCLS * TT * HH) / 256, 256, 0, stream>>>(fcw, fcwb, NCLS * TT * HH);
  bias_prep<<<(NLAYER * G4) / 256, 256, 0, stream>>>(bih0, bhh0, bih, bhh, biasb);
  zero_u32<<<(NLAYER * 64 + 64 + 255) / 256, 256, 0, stream>>>(
      flags, NLAYER * 64 + 64);

  lstm_all<<<256, 512, 131072, stream>>>(x, Wp, biasb, hring, h7, flags, xslot);

  fc_kernel<<<dim3(16, 16), 256, 0, stream>>>(h7, fcwb, part);
  fc_reduce<<<(BB * NCLS) / 256, 256, 0, stream>>>(part, fcb, out);
}

// Round 4
// 3642.966 us; speedup vs baseline: 1.3100x; 1.3100x over previous
//
#include <hip/hip_runtime.h>
#include <hip/hip_bf16.h>

#define BB   1024
#define TT   64
#define IND  64
#define HH   512
#define G4   2048   // 4*H
#define NLAYER 8
#define NCLS 128
#define KP   1024   // packed W k-stride: k<512 = W_hh, k>=512 = W_ih (layer0 64 + pad)
#define RS   8      // ring slots per layer (reuse distance 8 = fence period)
#define SLOT (32 * 1024 * 16)  // elements per h slot: [by=32][b=1024][jj=16]

typedef __bf16 bf16x8 __attribute__((ext_vector_type(8)));
typedef float  f32x4  __attribute__((ext_vector_type(4)));

typedef const __attribute__((address_space(1))) void* as1cvp;
typedef __attribute__((address_space(3))) void* as3vp;

__device__ __forceinline__ void gload16(void* lds, const void* g) {
  __builtin_amdgcn_global_load_lds((as1cvp)g, (as3vp)lds, 16, 0, 0);
}

__device__ __forceinline__ float sigmf(float x) { return 1.f / (1.f + __expf(-x)); }
__device__ __forceinline__ float tanhfast(float x) { return 2.f / (1.f + __expf(-2.f * x)) - 1.f; }

// ---------------- prep kernels ----------------
__global__ void cvt_kernel(const float* __restrict__ s, __bf16* __restrict__ d, int n) {
  int i = blockIdx.x * 256 + threadIdx.x;
  if (i < n) d[i] = (__bf16)s[i];
}

__global__ void pack_w(const float* __restrict__ whh0, const float* __restrict__ wih0,
                       const float* __restrict__ whh, const float* __restrict__ wih,
                       __bf16* __restrict__ Wp) {
  int i = blockIdx.x * 256 + threadIdx.x;  // 8*2048*1024
  int k = i & (KP - 1), n = (i >> 10) & 2047, l = i >> 21;
  float v;
  if (k < 512) v = (l == 0) ? whh0[n * 512 + k] : whh[((size_t)(l - 1) * G4 + n) * 512 + k];
  else if (l == 0) v = (k < 512 + IND) ? wih0[n * IND + (k - 512)] : 0.f;
  else v = wih[((size_t)(l - 1) * G4 + n) * 512 + (k - 512)];
  Wp[i] = (__bf16)v;
}

__global__ void bias_prep(const float* __restrict__ bi0, const float* __restrict__ bh0,
                          const float* __restrict__ bi, const float* __restrict__ bh,
                          float* __restrict__ biasb) {
  int i = blockIdx.x * 256 + threadIdx.x;  // 8*2048
  int l = i >> 11, k = i & 2047;
  float v = (l == 0) ? (bi0[k] + bh0[k]) : (bi[(l - 1) * G4 + k] + bh[(l - 1) * G4 + k]);
  biasb[i] = v;
}

__global__ void zero_u32(unsigned* __restrict__ p, int n) {
  int i = blockIdx.x * 256 + threadIdx.x;
  if (i < n) p[i] = 0u;
}

// ---------------- all-layers pipelined LSTM ----------------
// R14 = R12 (proven 4292us) with the x-part moved OFF the serial recurrence.
// R12's step window (own-barrier -> own-barrier) contained the full 32-kt
// K-loop; flag propagation, pipe restarts and slowest-block tails were all
// serialized with all the compute. The x-part (W_ih . h_up[t]) depends only on
// upstream data (available a step early via the RS=8 ring), NOT on h[t-1].
// New schedule per step:
//   own-poll(t) -> h-part(t) -> epilogue -> store h[t] -> flag(t+1)
//   -> up-poll(t+2) -> acc=bias; x-part(t+1)         (the former dead zone)
// The layer cadence now contains only h-part+epilogue+store; the ~15us x-part
// covers flag propagation + jitter. Upstream coupling tightens to up>=t+2
// (ring slack 8->6, back-pressure invariant verified: the last reader of own
// slot-gen(t-8) completes its read before flagging t-7, which is what the
// down-poll certifies). Fence cadence (one acquire per 8-step period between
// same-address re-reads) preserved. Per-accumulator MFMA order unchanged
// (bias -> x-part kt0..15 -> h-part kt0..15) -> bit-identical numerics to R12.
__global__ __launch_bounds__(256, 2) void lstm_all(
    const float* __restrict__ xf,      // [B][T][64] fp32
    const __bf16* __restrict__ Wp,     // [8][2048][KP]
    const float* __restrict__ biasb,   // [8][2048]
    __bf16* __restrict__ hring,        // [7][RS][SLOT]
    __bf16* __restrict__ h7,           // [64][SLOT]
    unsigned* __restrict__ flags,      // [8][2][64] (32 used per group)
    unsigned* __restrict__ xslot) {    // [8]
  extern __shared__ __bf16 Wlds[];     // 64KB: 16 k-slices x (64 rows x 32 k)
  __shared__ int sbs;
  const int tid = threadIdx.x;

  if (tid == 0) {
    unsigned xcc;
    asm volatile("s_getreg_b32 %0, hwreg(HW_REG_XCC_ID)" : "=s"(xcc));
    xcc &= 7u;
    unsigned slot = __hip_atomic_fetch_add(xslot + xcc, 1u, __ATOMIC_RELAXED,
                                           __HIP_MEMORY_SCOPE_AGENT) & 63u;
    sbs = (int)((xcc << 6) | slot);
  }
  __syncthreads();
  const int l  = sbs >> 6;         // layer = XCD
  const int bx = (sbs >> 5) & 1;   // b-half (512 rows)
  const int by = sbs & 31;         // j-tile (16 j x 4 gates)
  const int j0 = by << 4;
  const __bf16* Wl = Wp + (size_t)l * G4 * KP;

  // ---- stage W_hh (64 n-rows x 512 k) into LDS, XOR-swizzled
  for (int it = 0; it < 16; ++it) {
    const int p = it * 256 + tid;           // granule 0..4095
    const int kt = p >> 8;
    const int q = p & 255;
    const int u = q >> 2;                   // row 0..63 (gate*16+jj)
    const int g = (q & 3) ^ ((u >> 1) & 3);
    const int n = ((u >> 4) << 9) + j0 + (u & 15);
    gload16(&Wlds[p * 8], Wl + (size_t)n * KP + kt * 32 + g * 8);
  }

  const int lane = tid & 63, wv = tid >> 6;
  const int qr = lane >> 4, ml = lane & 15;
  const __bf16* wb[4];
  float bv[4];
  int wsw[4];
#pragma unroll
  for (int g = 0; g < 4; ++g) {
    const int n = g * 512 + j0 + ml;
    wb[g] = Wl + (size_t)n * KP + 512 + qr * 8;   // W_ih (L2-resident on this XCD)
    bv[g] = biasb[l * G4 + n];
    const int u = g * 16 + ml;
    wsw[g] = u * 32 + ((qr ^ ((u >> 1) & 3)) << 3);
  }
  const int r0 = (bx << 9) + (wv << 7);   // wave's 128 rows (8 m-tiles of 16)
  const int rowA = r0 + ml;
  // A-frag base offset into a slot: (kt*2 + (qr>>1))*16384 + row*16 + (qr&1)*8
  const int abase = ((qr >> 1) << 14) + rowA * 16 + ((qr & 1) << 3);
  __bf16* ringL = hring + (size_t)l * RS * SLOT;                       // l<7
  const __bf16* ringU = hring + (size_t)((l > 0 ? l : 1) - 1) * RS * SLOT;
  unsigned* ownf = flags + (l * 2 + bx) * 64;
  unsigned* upf  = flags + ((l > 0 ? l - 1 : 0) * 2 + bx) * 64;
  unsigned* dnf  = flags + ((l < 7 ? l + 1 : 7) * 2 + bx) * 64;
  float c8[8][4] = {};
  f32x4 acc[8][4];
  __syncthreads();  // W_hh staged

  auto initAcc = [&]() {
#pragma unroll
    for (int m = 0; m < 8; ++m)
#pragma unroll
      for (int g = 0; g < 4; ++g)
#pragma unroll
        for (int r = 0; r < 4; ++r) acc[m][g][r] = bv[g];
  };

  // x-part for layer 0: direct fp32->bf16 from x[:, tx, :], K=64
  auto xpartL0 = [&](int tx) {
#pragma unroll
    for (int m = 0; m < 8; ++m) {
      const float* xr = xf + ((size_t)(rowA + m * 16) * TT + tx) * IND + qr * 8;
      const f32x4 f0 = *(const f32x4*)xr;
      const f32x4 f1 = *(const f32x4*)(xr + 4);
      const f32x4 f2 = *(const f32x4*)(xr + 32);
      const f32x4 f3 = *(const f32x4*)(xr + 36);
      bf16x8 a0, a1;
#pragma unroll
      for (int r = 0; r < 4; ++r) {
        a0[r] = (__bf16)f0[r]; a0[4 + r] = (__bf16)f1[r];
        a1[r] = (__bf16)f2[r]; a1[4 + r] = (__bf16)f3[r];
      }
#pragma unroll
      for (int g = 0; g < 4; ++g) {
        acc[m][g] = __builtin_amdgcn_mfma_f32_16x16x32_bf16(
            a0, *(const bf16x8*)(wb[g]), acc[m][g], 0, 0, 0);
        acc[m][g] = __builtin_amdgcn_mfma_f32_16x16x32_bf16(
            a1, *(const bf16x8*)(wb[g] + 32), acc[m][g], 0, 0, 0);
      }
    }
  };

  // x-part for l>0: A = upstream h[tx], half-kt pipelined, W_ih 2-set rotation
  auto xpartL = [&](int tx) {
    const __bf16* src = ringU + (size_t)(tx & (RS - 1)) * SLOT + abase;
    bf16x8 A0[4], A1[4], Wr[2][4];
#pragma unroll
    for (int m = 0; m < 4; ++m) A0[m] = *(const bf16x8*)(src + m * 256);
#pragma unroll
    for (int m = 0; m < 4; ++m) A1[m] = *(const bf16x8*)(src + (4 + m) * 256);
#pragma unroll
    for (int g = 0; g < 4; ++g) Wr[0][g] = *(const bf16x8*)(wb[g]);
#pragma unroll
    for (int kt = 0; kt < 16; ++kt) {
      const __bf16* aknx = src + (kt + 1) * 32768;
#pragma unroll
      for (int m = 0; m < 4; ++m)
#pragma unroll
        for (int g = 0; g < 4; ++g)
          acc[m][g] = __builtin_amdgcn_mfma_f32_16x16x32_bf16(
              A0[m], Wr[kt & 1][g], acc[m][g], 0, 0, 0);
      if (kt < 15) {
#pragma unroll
        for (int m = 0; m < 4; ++m) A0[m] = *(const bf16x8*)(aknx + m * 256);
#pragma unroll
        for (int g = 0; g < 4; ++g)
          Wr[(kt + 1) & 1][g] = *(const bf16x8*)(wb[g] + (kt + 1) * 32);
      }
      __builtin_amdgcn_sched_barrier(0);
#pragma unroll
      for (int m = 0; m < 4; ++m)
#pragma unroll
        for (int g = 0; g < 4; ++g)
          acc[4 + m][g] = __builtin_amdgcn_mfma_f32_16x16x32_bf16(
              A1[m], Wr[kt & 1][g], acc[4 + m][g], 0, 0, 0);
      if (kt < 15) {
#pragma unroll
        for (int m = 0; m < 4; ++m) A1[m] = *(const bf16x8*)(aknx + (4 + m) * 256);
      }
      __builtin_amdgcn_sched_barrier(0);
    }
  };

  // h-part: A = own h[t-1], half-kt pipelined, W_hh JIT from LDS
  auto hpart = [&](int t) {
    const __bf16* srcH = ((l < 7) ? ringL + (size_t)((t - 1) & (RS - 1)) * SLOT
                                  : h7 + (size_t)(t - 1) * SLOT) + abase;
    bf16x8 A0[4], A1[4];
#pragma unroll
    for (int m = 0; m < 4; ++m) A0[m] = *(const bf16x8*)(srcH + m * 256);
#pragma unroll
    for (int m = 0; m < 4; ++m) A1[m] = *(const bf16x8*)(srcH + (4 + m) * 256);
#pragma unroll
    for (int kt = 0; kt < 16; ++kt) {
      const __bf16* aknx = srcH + (kt + 1) * 32768;
      bf16x8 wf[4];
#pragma unroll
      for (int g = 0; g < 4; ++g) wf[g] = *(const bf16x8*)&Wlds[kt * 2048 + wsw[g]];
#pragma unroll
      for (int m = 0; m < 4; ++m)
#pragma unroll
        for (int g = 0; g < 4; ++g)
          acc[m][g] = __builtin_amdgcn_mfma_f32_16x16x32_bf16(
              A0[m], wf[g], acc[m][g], 0, 0, 0);
      if (kt < 15) {
#pragma unroll
        for (int m = 0; m < 4; ++m) A0[m] = *(const bf16x8*)(aknx + m * 256);
      }
      __builtin_amdgcn_sched_barrier(0);
#pragma unroll
      for (int m = 0; m < 4; ++m)
#pragma unroll
        for (int g = 0; g < 4; ++g)
          acc[4 + m][g] = __builtin_amdgcn_mfma_f32_16x16x32_bf16(
              A1[m], wf[g], acc[4 + m][g], 0, 0, 0);
      if (kt < 15) {
#pragma unroll
        for (int m = 0; m < 4; ++m) A1[m] = *(const bf16x8*)(aknx + (4 + m) * 256);
      }
      __builtin_amdgcn_sched_barrier(0);
    }
  };

  // ---- prologue: wait for upstream slot 0, compute x-part(0)
  if (l > 0) {
    if (wv == 0) {
      for (;;) {
        unsigned v = (lane < 32) ? __hip_atomic_load(upf + lane, __ATOMIC_RELAXED,
                                                     __HIP_MEMORY_SCOPE_AGENT)
                                 : 1u;
        if (__all((int)(v >= 1u))) break;
        __builtin_amdgcn_s_sleep(1);
      }
    }
    __syncthreads();
  }
  initAcc();
  if (l == 0) xpartL0(0); else xpartL(0);

  for (int t = 0; t < TT; ++t) {
    // ---- B1: own-recurrence wait (all 32 by-blocks of this (l,bx) at >= t)
    if (wv == 0 && t > 0) {
      const unsigned need = (unsigned)t;
      for (;;) {
        unsigned v = (lane < 32) ? __hip_atomic_load(ownf + lane, __ATOMIC_RELAXED,
                                                     __HIP_MEMORY_SCOPE_AGENT)
                                 : need;
        if (__all((int)(v >= need))) break;
        __builtin_amdgcn_s_sleep(1);
      }
    }
    __syncthreads();
    if (t > 0 && (t & (RS - 1)) == 0)
      __builtin_amdgcn_fence(__ATOMIC_ACQUIRE, "agent");  // once per ring period

    // ---- h-part (t>0): acc already holds bias + x-part(t)
    if (t > 0) hpart(t);

    // ---- ring back-pressure (overwrite slot t&7 only after downstream read gen t-8)
    if (wv == 0 && l < 7 && t >= RS) {
      const unsigned need = (unsigned)(t - (RS - 1));
      for (;;) {
        unsigned v = (lane < 32) ? __hip_atomic_load(dnf + lane, __ATOMIC_RELAXED,
                                                     __HIP_MEMORY_SCOPE_AGENT)
                                 : need;
        if (__all((int)(v >= need))) break;
        __builtin_amdgcn_s_sleep(1);
      }
    }
    __syncthreads();  // B2

    // ---- activations + h store: [by][b][16] panel -> contiguous 32B granules
    unsigned short* dst = (unsigned short*)(((l < 7)
        ? ringL + (size_t)(t & (RS - 1)) * SLOT
        : h7 + (size_t)t * SLOT) + ((size_t)by << 14)) + ml;
#pragma unroll
    for (int m = 0; m < 8; ++m) {
      const int rbm = r0 + m * 16 + (qr << 2);
#pragma unroll
      for (int r = 0; r < 4; ++r) {
        const float gi = sigmf(acc[m][0][r]);
        const float gf = sigmf(acc[m][1][r]);
        const float gg = tanhfast(acc[m][2][r]);
        const float go = sigmf(acc[m][3][r]);
        const float cv = gf * c8[m][r] + gi * gg;
        c8[m][r] = cv;
        const __bf16 hv = (__bf16)(go * tanhfast(cv));
        __hip_atomic_store(dst + (size_t)(rbm + r) * 16,
                           __builtin_bit_cast(unsigned short, hv),
                           __ATOMIC_RELAXED, __HIP_MEMORY_SCOPE_AGENT);
      }
    }
    __syncthreads();  // B3: drains vmcnt -> stores at coherence point
    if (tid == 0)
      __hip_atomic_store(ownf + by, (unsigned)(t + 1), __ATOMIC_RELAXED,
                         __HIP_MEMORY_SCOPE_AGENT);

    // ---- dead-zone work: x-part of step t+1 (covers flag propagation + tails)
    if (t + 1 < TT) {
      if (l > 0) {
        if (wv == 0) {
          const unsigned need = (unsigned)(t + 2);
          for (;;) {
            unsigned v = (lane < 32) ? __hip_atomic_load(upf + lane, __ATOMIC_RELAXED,
                                                         __HIP_MEMORY_SCOPE_AGENT)
                                     : need;
            if (__all((int)(v >= need))) break;
            __builtin_amdgcn_s_sleep(1);
          }
        }
        __syncthreads();
      }
      initAcc();
      if (l == 0) xpartL0(t + 1); else xpartL(t + 1);
    }
  }
}

// ---------------- FC (bf16 MFMA, K-split; h7 in [t][by][b][16] layout) ----------------
__global__ __launch_bounds__(256, 2) void fc_kernel(
    const __bf16* __restrict__ hseq, const __bf16* __restrict__ fcw,
    float* __restrict__ partial) {
  __shared__ __bf16 At[64 * 32];
  __shared__ __bf16 Wt[128 * 32];
  const int tid = threadIdx.x;
  const int b0 = blockIdx.x * 64;
  const int kbase = blockIdx.y * 2048;
  const int lane = tid & 63, wv = tid >> 6;
  const int qr = lane >> 4, ml = lane & 15;
  const int wr = (wv >> 1) * 32, wc = (wv & 1) * 64;
  const int sr = tid >> 2, sk = (tid & 3) * 8;

  f32x4 acc[2][4];
  for (int i = 0; i < 2; i++)
    for (int j = 0; j < 4; j++)
      for (int r = 0; r < 4; r++) acc[i][j][r] = 0.f;

  for (int kt = 0; kt < 64; ++kt) {
    const int k = kbase + kt * 32;
    const int t = k >> 9;
    const int kk = (k & 511) + sk;      // global j index of this 8-elem chunk
    gload16(&At[tid * 8],
            hseq + (size_t)t * SLOT + ((size_t)(kk >> 4) * 1024 + b0 + sr) * 16 + (kk & 15));
    gload16(&Wt[tid * 8],        fcw + (size_t)sr * (TT * HH) + k + sk);
    gload16(&Wt[2048 + tid * 8], fcw + (size_t)(sr + 64) * (TT * HH) + k + sk);
    __syncthreads();
    bf16x8 af[2], bfr[4];
    for (int i = 0; i < 2; i++) af[i]  = *(const bf16x8*)&At[(wr + i * 16 + ml) * 32 + qr * 8];
    for (int j = 0; j < 4; j++) bfr[j] = *(const bf16x8*)&Wt[(wc + j * 16 + ml) * 32 + qr * 8];
    for (int i = 0; i < 2; i++)
      for (int j = 0; j < 4; j++)
        acc[i][j] = __builtin_amdgcn_mfma_f32_16x16x32_bf16(af[i], bfr[j], acc[i][j], 0, 0, 0);
    __syncthreads();
  }
  for (int i = 0; i < 2; i++)
    for (int j = 0; j < 4; j++)
      for (int r = 0; r < 4; r++)
        partial[((size_t)blockIdx.y * BB + b0 + wr + i * 16 + qr * 4 + r) * NCLS + wc + j * 16 + ml] =
            acc[i][j][r];
}

__global__ void fc_reduce(const float* __restrict__ partial, const float* __restrict__ fcb,
                          float* __restrict__ out) {
  int i = blockIdx.x * 256 + threadIdx.x;  // B*128
  float s = fcb[i & 127];
  for (int p = 0; p < 16; p++) s += partial[(size_t)p * (BB * NCLS) + i];
  out[i] = s;
}

// ---------------- host ----------------
extern "C" void kernel_launch(void* const* d_in, const int* in_sizes, int n_in,
                              void* d_out, int out_size, void* d_ws, size_t ws_size,
                              hipStream_t stream) {
  const float* x    = (const float*)d_in[0];
  const float* wih0 = (const float*)d_in[1];
  const float* whh0 = (const float*)d_in[2];
  const float* bih0 = (const float*)d_in[3];
  const float* bhh0 = (const float*)d_in[4];
  const float* wih  = (const float*)d_in[5];
  const float* whh  = (const float*)d_in[6];
  const float* bih  = (const float*)d_in[7];
  const float* bhh  = (const float*)d_in[8];
  const float* fcw  = (const float*)d_in[9];
  const float* fcb  = (const float*)d_in[10];
  float* out = (float*)d_out;

  hipFuncSetAttribute((const void*)lstm_all,
                      hipFuncAttributeMaxDynamicSharedMemorySize, 65536);

  size_t off = 0;
  char* base = (char*)d_ws;
  auto carve = [&](size_t bytes) -> char* {
    char* p = base + off;
    off += (bytes + 255) & ~(size_t)255;
    return p;
  };
  // total ~176 MB (< proven 193 MB budget)
  __bf16*   Wp    = (__bf16*)carve((size_t)NLAYER * G4 * KP * 2);      // 33.6 MB
  __bf16*   fcwb  = (__bf16*)carve((size_t)NCLS * TT * HH * 2);        //  8.4 MB
  float*    biasb = (float*)carve((size_t)NLAYER * G4 * 4);
  __bf16*   hring = (__bf16*)carve((size_t)7 * RS * SLOT * 2);         // 58.7 MB
  __bf16*   h7    = (__bf16*)carve((size_t)TT * SLOT * 2);             // 67.1 MB
  float*    part  = (float*)carve((size_t)16 * BB * NCLS * 4);         //  8.4 MB
  unsigned* flags = (unsigned*)carve((size_t)(NLAYER * 2 * 64 + 64) * 4);
  unsigned* xslot = flags + NLAYER * 2 * 64;

  // prep
  pack_w<<<(NLAYER * G4 * KP) / 256, 256, 0, stream>>>(whh0, wih0, whh, wih, Wp);
  cvt_kernel<<<(NCLS * TT * HH) / 256, 256, 0, stream>>>(fcw, fcwb, NCLS * TT * HH);
  bias_prep<<<(NLAYER * G4) / 256, 256, 0, stream>>>(bih0, bhh0, bih, bhh, biasb);
  zero_u32<<<(NLAYER * 2 * 64 + 64 + 255) / 256, 256, 0, stream>>>(
      flags, NLAYER * 2 * 64 + 64);

  lstm_all<<<512, 256, 65536, stream>>>(x, Wp, biasb, hring, h7, flags, xslot);

  fc_kernel<<<dim3(16, 16), 256, 0, stream>>>(h7, fcwb, part);
  fc_reduce<<<(BB * NCLS) / 256, 256, 0, stream>>>(part, fcb, out);
}